// Round 1
// 121.987 us; speedup vs baseline: 1.0012x; 1.0012x over previous
//
#include <hip/hip_runtime.h>

#define B_ 128
#define O_ 1024
#define I_ 1024
#define NCHUNK 64
#define CI (I_ / NCHUNK)     // 16 i-values per wave
#define WPB 4                // waves per block
#define TT_BYTES ((size_t)O_ * I_ * sizeof(float))

#define LOG2E_F  1.4426950408889634f
#define LN2_F    0.6931471805599453f
#define LN2SQ_F  0.4804530139182014f          // ln2^2
#define EPSC_F   (1e-7f * LN2SQ_F)            // eps * ln2^2

typedef float v2f __attribute__((ext_vector_type(2)));

__device__ __forceinline__ float fast_rsq(float x)  { return __builtin_amdgcn_rsqf(x); }
__device__ __forceinline__ float fast_exp2(float x) { return __builtin_amdgcn_exp2f(x); }
__device__ __forceinline__ float fast_rcp(float x)  { return __builtin_amdgcn_rcpf(x); }

// wave-uniform value -> SGPR
__device__ __forceinline__ float rfl(float x) {
    return __builtin_bit_cast(float,
        __builtin_amdgcn_readfirstlane(__builtin_bit_cast(int, x)));
}

// DPP add step (ctrl must be an immediate -> template param);
// bound_ctrl=true: invalid sources read 0.
template <int CTRL>
__device__ __forceinline__ float dpp_add(float v) {
    int x = __builtin_amdgcn_update_dpp(0, __builtin_bit_cast(int, v),
                                        CTRL, 0xf, 0xf, true);
    return v + __builtin_bit_cast(float, x);
}
// 64-lane sum; total lands in lane 63, returned as SGPR-uniform float.
__device__ __forceinline__ float wave_sum_uniform(float v) {
    v = dpp_add<0xB1>(v);   // quad_perm [1,0,3,2] : pair sums
    v = dpp_add<0x4E>(v);   // quad_perm [2,3,0,1] : quad sums
    v = dpp_add<0x141>(v);  // row_half_mirror     : octet sums
    v = dpp_add<0x140>(v);  // row_mirror          : row-of-16 sums
    v = dpp_add<0x142>(v);  // row_bcast15         : rows 1..3 += prev row
    v = dpp_add<0x143>(v);  // row_bcast31         : rows 2,3 += rows 0+1
    return __builtin_bit_cast(float,
        __builtin_amdgcn_readlane(__builtin_bit_cast(int, v), 63));
}

// ---------------------------------------------------------------------------
// Fused kernel 1: Tt2[i*O+o] = T[o,i]^2 (transposed+squared), plus
//  - per-column(i) min via LDS-pre-reduced global atomicMin on uint bits
//    (valid: r2 >= 0 so float bits are monotone as unsigned),
//  - zeroing of d_out (grid 1024 blocks x 128 elems = 131072 = B*O).
// ---------------------------------------------------------------------------
__global__ __launch_bounds__(256) void build_T2_kernel(
    const float* __restrict__ ix, const float* __restrict__ iy,
    const float* __restrict__ ox, const float* __restrict__ oy,
    const float* __restrict__ la, const float* __restrict__ lm,
    float* __restrict__ Tt2, unsigned* __restrict__ minbits,
    float* __restrict__ out_zero)
{
    __shared__ float tile[32][33];
    __shared__ unsigned mloc[32];
    const int i0 = blockIdx.x * 32;
    const int o0 = blockIdx.y * 32;
    const int tx = threadIdx.x;      // 0..31
    const int ty = threadIdx.y;      // 0..7
    const int t  = ty * 32 + tx;     // 0..255

    if (t < 32) mloc[t] = 0xFFFFFFFFu;

    // fold the d_out zeroing in (saves a memset dispatch)
    const int bid = blockIdx.y * gridDim.x + blockIdx.x;   // 0..1023
    if (t < 128) out_zero[bid * 128 + t] = 0.0f;

#pragma unroll
    for (int r = 0; r < 32; r += 8) {
        const int o = o0 + ty + r;
        const int i = i0 + tx;
        const int idx = o * I_ + i;
        const float tt = fmaf(ix[idx] * fast_rcp(iy[idx]) + la[idx],
                              1.0f + lm[idx],
                              -(ox[idx] * fast_rcp(oy[idx])));
        tile[ty + r][tx] = tt * tt;
    }
    __syncthreads();
#pragma unroll
    for (int r = 0; r < 32; r += 8) {
        const int i = i0 + ty + r;
        const int o = o0 + tx;
        Tt2[i * O_ + o] = tile[tx][ty + r];
    }
    // per-i min over this block's 32 o's: thread t covers i_local=t&31,
    // o_locals = (t>>5)*4 .. +3
    const int il = t & 31;
    const int g  = t >> 5;
    float mn = fminf(fminf(tile[4 * g + 0][il], tile[4 * g + 1][il]),
                     fminf(tile[4 * g + 2][il], tile[4 * g + 3][il]));
    atomicMin(&mloc[il], __builtin_bit_cast(unsigned, mn));
    __syncthreads();
    if (t < 32) atomicMin(&minbits[i0 + t], mloc[t]);
}

// ---------------------------------------------------------------------------
// Kernel 2: wave owns chunk of 16 i's; lane owns 16 o's. Prologue hoists all
// wave-uniform per-i values into SGPRs. Main loop is SOFTWARE-PIPELINED:
// iteration ii computes the trans-heavy e/z for i=ii, then (data-independent)
// performs the serial DPP z-reduce + scale + acc-apply for i=ii-1, so the
// scheduler can fill the reduce chain's latency with this iteration's
// rsq/exp2 issues instead of stalling the wave.
// ---------------------------------------------------------------------------
__global__ __launch_bounds__(256) void aeg_main_kernel(
    const float* __restrict__ data,   // (B, I)
    const float* __restrict__ Tt2,    // (I, O) transposed T^2
    const float* __restrict__ minr2,  // (I) float bits (from atomicMin)
    float* __restrict__ out)          // (B, O), zeroed by build_T2
{
    __shared__ float red[WPB][O_];    // 16 KB

    const int w    = threadIdx.x >> 6;
    const int lane = threadIdx.x & 63;
    const int chunk = blockIdx.x * WPB + w;
    const int b     = blockIdx.y;

    const float4* rowbase = (const float4*)(Tt2 + (size_t)chunk * CI * O_);

    // ---- prologue: hoist all wave-uniform loads/derivations into SGPRs ----
    const float4* dv4 = (const float4*)(data + b * I_ + chunk * CI);
    const float4* mr4 = (const float4*)(minr2 + chunk * CI);
    float sdv[CI], ss2[CI], sm2[CI];
#pragma unroll
    for (int k = 0; k < 4; ++k) {
        const float4 a = dv4[k];
        const float4 m = mr4[k];
        const float av[4] = {a.x, a.y, a.z, a.w};
        const float mv[4] = {m.x, m.y, m.z, m.w};
#pragma unroll
        for (int jj = 0; jj < 4; ++jj) {
            const int j = 4 * k + jj;
            const float dv  = av[jj];
            const float sig = fast_rcp(1.0f + fast_exp2(-dv * LOG2E_F));
            const float sc  = sig * LN2_F;
            const float s2  = sc * sc;
            const float m2  = fast_rsq(fmaf(mv[jj], s2, EPSC_F)); // exact max
            sdv[j] = rfl(dv);
            ss2[j] = rfl(s2);
            sm2[j] = rfl(m2);
        }
    }

    v2f acc2[8];
#pragma unroll
    for (int j = 0; j < 8; ++j) acc2[j] = (v2f)0.0f;

    float4 rr[2][4];
#pragma unroll
    for (int k = 0; k < 4; ++k) rr[0][k] = rowbase[lane + 64 * k];

    // trans-heavy body: computes e (into e2) and returns the per-lane z partial
    auto compute = [&](const float4* r, const v2f s2v, const v2f m2v,
                       v2f* e2) -> v2f {
        const v2f epv = {EPSC_F, EPSC_F};
        v2f zv0 = (v2f)0.0f, zv1 = (v2f)0.0f;
#pragma unroll
        for (int k = 0; k < 4; ++k) {
            const v2f a = {r[k].x, r[k].y};
            const v2f c = {r[k].z, r[k].w};
            const v2f q0 = a * s2v + epv;
            const v2f q1 = c * s2v + epv;
            v2f t0, t1;
            t0.x = fast_rsq(q0.x); t0.y = fast_rsq(q0.y);
            t1.x = fast_rsq(q1.x); t1.y = fast_rsq(q1.y);
            t0 -= m2v;
            t1 -= m2v;
            v2f ev0, ev1;
            ev0.x = fast_exp2(t0.x); ev0.y = fast_exp2(t0.y);
            ev1.x = fast_exp2(t1.x); ev1.y = fast_exp2(t1.y);
            e2[2 * k]     = ev0;
            e2[2 * k + 1] = ev1;
            zv0 += ev0;
            zv1 += ev1;
        }
        return zv0 + zv1;
    };

    v2f e2p[8];                 // previous iteration's e values (deferred apply)
    v2f zvp;                    // previous iteration's z partial

    // ---- pipeline prologue: i = 0 ----
    {
#pragma unroll
        for (int k = 0; k < 4; ++k) rr[1][k] = rowbase[(O_ / 4) + lane + 64 * k];
        const v2f s2v = {ss2[0], ss2[0]};
        const v2f m2v = {sm2[0], sm2[0]};
        zvp = compute(rr[0], s2v, m2v, e2p);
    }

#pragma unroll
    for (int ii = 1; ii < CI; ++ii) {
        // prefetch row ii+1
        if (ii + 1 < CI) {
            const float4* nrow = rowbase + (size_t)(ii + 1) * (O_ / 4);
#pragma unroll
            for (int k = 0; k < 4; ++k) rr[(ii + 1) & 1][k] = nrow[lane + 64 * k];
        }

        // compute current (trans-heavy, independent of previous reduce)
        v2f e2c[8];
        const v2f s2v = {ss2[ii], ss2[ii]};
        const v2f m2v = {sm2[ii], sm2[ii]};
        const v2f zvc = compute(rr[ii & 1], s2v, m2v, e2c);

        // apply previous: serial DPP reduce overlaps with the trans ops above
        const float zt = wave_sum_uniform(zvp.x + zvp.y);    // SGPR-uniform
        const float scale = sdv[ii - 1] * fast_rcp(zt);      // z >= 1
        const v2f sc2 = {scale, scale};
#pragma unroll
        for (int j = 0; j < 8; ++j)
            acc2[j] = e2p[j] * sc2 + acc2[j];

        // rotate pipeline registers (renamed away by unroll)
#pragma unroll
        for (int j = 0; j < 8; ++j) e2p[j] = e2c[j];
        zvp = zvc;
    }

    // ---- pipeline epilogue: apply i = CI-1 ----
    {
        const float zt = wave_sum_uniform(zvp.x + zvp.y);
        const float scale = sdv[CI - 1] * fast_rcp(zt);
        const v2f sc2 = {scale, scale};
#pragma unroll
        for (int j = 0; j < 8; ++j)
            acc2[j] = e2p[j] * sc2 + acc2[j];
    }

    // Stage per-wave accumulators, reduce across the 4 waves in LDS.
#pragma unroll
    for (int k = 0; k < 4; ++k) {
        float4 v;
        v.x = acc2[2 * k].x;     v.y = acc2[2 * k].y;
        v.z = acc2[2 * k + 1].x; v.w = acc2[2 * k + 1].y;
        ((float4*)&red[w][256 * k])[lane] = v;
    }
    __syncthreads();

    const int t = threadIdx.x;
    float4 v = ((const float4*)red[0])[t];
#pragma unroll
    for (int ww = 1; ww < WPB; ++ww) {
        const float4 u = ((const float4*)red[ww])[t];
        v.x += u.x; v.y += u.y; v.z += u.z; v.w += u.w;
    }
    float* ob = out + b * O_ + 4 * t;
    atomicAdd(&ob[0], v.x);
    atomicAdd(&ob[1], v.y);
    atomicAdd(&ob[2], v.z);
    atomicAdd(&ob[3], v.w);
}

// ---------------------------------------------------------------------------
extern "C" void kernel_launch(void* const* d_in, const int* in_sizes, int n_in,
                              void* d_out, int out_size, void* d_ws, size_t ws_size,
                              hipStream_t stream)
{
    const float* data = (const float*)d_in[0];
    const float* ix   = (const float*)d_in[1];
    const float* iy   = (const float*)d_in[2];
    const float* ox   = (const float*)d_in[3];
    const float* oy   = (const float*)d_in[4];
    const float* la   = (const float*)d_in[5];
    const float* lm   = (const float*)d_in[6];
    float* out  = (float*)d_out;
    float* Tt2  = (float*)d_ws;
    unsigned* minbits = (unsigned*)((char*)d_ws + TT_BYTES);

    // init min accumulators to UINT_MAX (tiny; the only extra dispatch)
    (void)hipMemsetAsync(minbits, 0xFF, I_ * sizeof(unsigned), stream);

    build_T2_kernel<<<dim3(I_ / 32, O_ / 32), dim3(32, 8), 0, stream>>>(
        ix, iy, ox, oy, la, lm, Tt2, minbits, out);

    aeg_main_kernel<<<dim3(NCHUNK / WPB, B_), 256, 0, stream>>>(
        data, Tt2, (const float*)minbits, out);
}